// Round 8
// baseline (127.960 us; speedup 1.0000x reference)
//
#include <hip/hip_runtime.h>
#include <hip/hip_bf16.h>

// FullAttention: B=2, C=64, Cq=8, N=20^3=8000. Inputs CONFIRMED f32 (r2).
#define BB 2
#define CC 64
#define CQk 8
#define NN 8000
#define QT 4          // 16-row q-tiles per wave (64 q per block)
#define NWAVE 8
#define NBLK32 250    // 8000/32 m-blocks

using f32x4  = __attribute__((ext_vector_type(4))) float;
using bf16x8 = __attribute__((ext_vector_type(8))) short;
typedef unsigned short ushort_t;
typedef unsigned int uint_t;

__device__ __forceinline__ ushort_t f2bf(float f) {
    __hip_bfloat16 h = __float2bfloat16(f);
    return *reinterpret_cast<ushort_t*>(&h);
}

// 2^x via compiler-visible trans-op intrinsic (hazard-safe; raw asm NaN'd r5).
__device__ __forceinline__ float exp2_fast(float x) {
#if __has_builtin(__builtin_amdgcn_exp2f)
    return __builtin_amdgcn_exp2f(x);
#else
    return exp2f(x);
#endif
}

// pack two f32 -> u32 of 2 bf16 (round-half-up). Valid for finite positives.
__device__ __forceinline__ uint_t pack_bf16(float a, float b) {
    const uint_t ua = __builtin_bit_cast(uint_t, a) + 0x8000u;
    const uint_t ub = __builtin_bit_cast(uint_t, b) + 0x8000u;
    return (ua >> 16) | (ub & 0xFFFF0000u);
}

// ---------------------------------------------------------------------------
__global__ void detect_dtype(const void* __restrict__ x, int* __restrict__ flag)
{
    const float* xf = (const float*)x;
    const int t = threadIdx.x;
    const float a = fabsf(xf[t * 8]);
    const int ok = (a > 9.765625e-4f && a < 16.0f) ? 1 : 0;
    const unsigned long long m = __ballot(ok);
    if (t == 0) flag[0] = (__popcll(m) >= 48) ? 1 : 0;
}

__device__ __forceinline__ float loadF(const void* p, size_t i, int isf) {
    return isf ? ((const float*)p)[i]
               : __bfloat162float(((const __hip_bfloat16*)p)[i]);
}

// ---------------------------------------------------------------------------
// Kernel 1: QKV projection -> FRAGMENT-MAJOR K/V so attn loads are lane*16B
// coalesced. 250 blocks x 640 thr (10 waves). Wave rg: rows rg*8..rg*8+7.
//   Qbf  [b][n][8]                       (prescaled log2e)
//   Kfrag[b][mblk][j][lane=h*16+cl][8]   lane h=0 holds K[m0+j*16+cl][0..7], h>0 zeros
//   Vfrag[b][mblk][ct][lane=h*16+cl][8]  elem e = V[c=ct*16+cl][pv=h*8+e permuted]
// (permutation pv: n -> hv*8+iv, hv=(n&15)>>2, iv=(n&3)+(((n>>4)&1)<<2) — r4/r6-verified)
// ---------------------------------------------------------------------------
__global__ __launch_bounds__(640) void qkv_kernel(
    const void* __restrict__ x,
    const void* __restrict__ Wq, const void* __restrict__ bq,
    const void* __restrict__ Wk, const void* __restrict__ bk,
    const void* __restrict__ Wv, const void* __restrict__ bv,
    ushort_t* __restrict__ Qbf, ushort_t* __restrict__ Kfrag,
    ushort_t* __restrict__ Vfrag, const int* __restrict__ flag)
{
    __shared__ float sW[80][CC];
    __shared__ float sB[80];
    __shared__ float sX[CC][64];
    const int isf = flag[0];
    const int t = threadIdx.x;

    for (int i = t; i < 80 * CC; i += 640) {
        const int r = i >> 6, c = i & 63;
        float w;
        if (r < CQk)          w = loadF(Wq, (size_t)r * CC + c, isf);
        else if (r < 2 * CQk) w = loadF(Wk, (size_t)(r - CQk) * CC + c, isf);
        else                  w = loadF(Wv, (size_t)(r - 2 * CQk) * CC + c, isf);
        sW[r][c] = w;
    }
    if (t < 80) {
        float bias;
        if (t < CQk)          bias = loadF(bq, t, isf);
        else if (t < 2 * CQk) bias = loadF(bk, t - CQk, isf);
        else                  bias = loadF(bv, t - 2 * CQk, isf);
        sB[t] = bias;
    }
    const int blk = blockIdx.x;            // 0..249 (125 per batch)
    const int b = blk / 125;
    const int n0 = (blk % 125) * 64;
    for (int i = t; i < CC * 64; i += 640) {
        const int c = i >> 6, nl = i & 63;
        sX[c][nl] = loadF(x, (size_t)b * CC * NN + (size_t)c * NN + n0 + nl, isf);
    }
    __syncthreads();

    const int rg = t >> 6;                 // wave 0..9 -> rows rg*8..+7
    const int nl = t & 63;
    const int n = n0 + nl;                 // batch-local position
    const int r0 = rg * 8;

    float xv[CC];
#pragma unroll
    for (int c = 0; c < CC; ++c) xv[c] = sX[c][nl];

    float acc[8];
#pragma unroll
    for (int rr = 0; rr < 8; ++rr) {
        const f32x4* w4 = (const f32x4*)&sW[r0 + rr][0];
        float a0 = 0.f, a1 = 0.f, a2 = 0.f, a3 = 0.f;
#pragma unroll
        for (int c4 = 0; c4 < 16; ++c4) {
            const f32x4 wv = w4[c4];
            a0 += wv.x * xv[c4 * 4 + 0];
            a1 += wv.y * xv[c4 * 4 + 1];
            a2 += wv.z * xv[c4 * 4 + 2];
            a3 += wv.w * xv[c4 * 4 + 3];
        }
        acc[rr] = sB[r0 + rr] + ((a0 + a1) + (a2 + a3));
    }

    const int mblk = n >> 5;
    if (rg == 0) {                         // Q rows 0..7
        bf16x8 pq;
#pragma unroll
        for (int j = 0; j < 8; ++j) pq[j] = (short)f2bf(acc[j] * 1.44269504089f);
        *(bf16x8*)&Qbf[((size_t)b * NN + n) * 8] = pq;
    } else if (rg == 1) {                  // K rows 8..15
        bf16x8 pk, z8;
#pragma unroll
        for (int j = 0; j < 8; ++j) { pk[j] = (short)f2bf(acc[j]); z8[j] = 0; }
        const int rloc = n & 31, jj = rloc >> 4, cl16 = rloc & 15;
        ushort_t* kb = Kfrag + (size_t)b * NN * 32
                     + ((size_t)(mblk * 2 + jj) * 64) * 8;
        *(bf16x8*)&kb[(cl16) * 8]      = pk;   // lane h=0
        *(bf16x8*)&kb[(16 + cl16) * 8] = z8;   // h=1..3 zero-pad
        *(bf16x8*)&kb[(32 + cl16) * 8] = z8;
        *(bf16x8*)&kb[(48 + cl16) * 8] = z8;
    } else {                               // V channels (rg-2)*8 .. +7
        const int c0 = (rg - 2) * 8;
        const int hv = (n & 15) >> 2;
        const int iv = (n & 3) + (((n >> 4) & 1) << 2);
        ushort_t* vb = Vfrag + (size_t)b * NN * 64;
#pragma unroll
        for (int rr = 0; rr < 8; ++rr) {
            const int c = c0 + rr;
            vb[((size_t)(mblk * 4 + (c >> 4)) * 64 + hv * 16 + (c & 15)) * 8 + iv]
                = f2bf(acc[rr]);
        }
    }
}

// ---------------------------------------------------------------------------
// Kernel 2: fused MFMA flash attention. grid (125,B), 8 waves, 2-deep ping-pong.
// All K/V loads now lane*16B coalesced (1KB/instruction) from fragment layouts.
// ---------------------------------------------------------------------------
#define KSTEP (16 * 1024)   // 16 mblks * 2 j * 64 lanes * 8 elems
#define VSTEP (16 * 2048)   // 16 mblks * 4 ct * 64 lanes * 8 elems

#define LOADK(d0, d1, ko) do { \
    d0 = *(const bf16x8*)(Kb + (ko)); \
    d1 = *(const bf16x8*)(Kb + (ko) + 512); } while (0)

#define LOADV(v0, v1, v2, v3, vo) do { \
    v0 = *(const bf16x8*)(Vb + (vo)); \
    v1 = *(const bf16x8*)(Vb + (vo) + 512); \
    v2 = *(const bf16x8*)(Vb + (vo) + 1024); \
    v3 = *(const bf16x8*)(Vb + (vo) + 1536); } while (0)

#define MKAF(af, eA, eB) do { \
    union { uint_t u[4]; bf16x8 v; } _u; \
    _u.u[0] = pack_bf16(exp2_fast(eA[0]), exp2_fast(eA[1])); \
    _u.u[1] = pack_bf16(exp2_fast(eA[2]), exp2_fast(eA[3])); \
    _u.u[2] = pack_bf16(exp2_fast(eB[0]), exp2_fast(eB[1])); \
    _u.u[3] = pack_bf16(exp2_fast(eB[2]), exp2_fast(eB[3])); \
    af = _u.v; } while (0)

#define COMPUTE(ka0, ka1, v0, v1, v2, v3) do { \
    f32x4 e00 = __builtin_amdgcn_mfma_f32_16x16x32_bf16(ka0, qb[0], zf, 0, 0, 0); \
    f32x4 e10 = __builtin_amdgcn_mfma_f32_16x16x32_bf16(ka1, qb[0], zf, 0, 0, 0); \
    f32x4 e01 = __builtin_amdgcn_mfma_f32_16x16x32_bf16(ka0, qb[1], zf, 0, 0, 0); \
    f32x4 e11 = __builtin_amdgcn_mfma_f32_16x16x32_bf16(ka1, qb[1], zf, 0, 0, 0); \
    f32x4 e02 = __builtin_amdgcn_mfma_f32_16x16x32_bf16(ka0, qb[2], zf, 0, 0, 0); \
    f32x4 e12 = __builtin_amdgcn_mfma_f32_16x16x32_bf16(ka1, qb[2], zf, 0, 0, 0); \
    f32x4 e03 = __builtin_amdgcn_mfma_f32_16x16x32_bf16(ka0, qb[3], zf, 0, 0, 0); \
    f32x4 e13 = __builtin_amdgcn_mfma_f32_16x16x32_bf16(ka1, qb[3], zf, 0, 0, 0); \
    bf16x8 af0, af1, af2, af3; \
    MKAF(af0, e00, e10); MKAF(af1, e01, e11); \
    MKAF(af2, e02, e12); MKAF(af3, e03, e13); \
    acc[0][0] = __builtin_amdgcn_mfma_f32_16x16x32_bf16(af0, v0, acc[0][0], 0, 0, 0); \
    acc[0][1] = __builtin_amdgcn_mfma_f32_16x16x32_bf16(af0, v1, acc[0][1], 0, 0, 0); \
    acc[0][2] = __builtin_amdgcn_mfma_f32_16x16x32_bf16(af0, v2, acc[0][2], 0, 0, 0); \
    acc[0][3] = __builtin_amdgcn_mfma_f32_16x16x32_bf16(af0, v3, acc[0][3], 0, 0, 0); \
    lac[0]    = __builtin_amdgcn_mfma_f32_16x16x32_bf16(af0, ones, lac[0], 0, 0, 0); \
    acc[1][0] = __builtin_amdgcn_mfma_f32_16x16x32_bf16(af1, v0, acc[1][0], 0, 0, 0); \
    acc[1][1] = __builtin_amdgcn_mfma_f32_16x16x32_bf16(af1, v1, acc[1][1], 0, 0, 0); \
    acc[1][2] = __builtin_amdgcn_mfma_f32_16x16x32_bf16(af1, v2, acc[1][2], 0, 0, 0); \
    acc[1][3] = __builtin_amdgcn_mfma_f32_16x16x32_bf16(af1, v3, acc[1][3], 0, 0, 0); \
    lac[1]    = __builtin_amdgcn_mfma_f32_16x16x32_bf16(af1, ones, lac[1], 0, 0, 0); \
    acc[2][0] = __builtin_amdgcn_mfma_f32_16x16x32_bf16(af2, v0, acc[2][0], 0, 0, 0); \
    acc[2][1] = __builtin_amdgcn_mfma_f32_16x16x32_bf16(af2, v1, acc[2][1], 0, 0, 0); \
    acc[2][2] = __builtin_amdgcn_mfma_f32_16x16x32_bf16(af2, v2, acc[2][2], 0, 0, 0); \
    acc[2][3] = __builtin_amdgcn_mfma_f32_16x16x32_bf16(af2, v3, acc[2][3], 0, 0, 0); \
    lac[2]    = __builtin_amdgcn_mfma_f32_16x16x32_bf16(af2, ones, lac[2], 0, 0, 0); \
    acc[3][0] = __builtin_amdgcn_mfma_f32_16x16x32_bf16(af3, v0, acc[3][0], 0, 0, 0); \
    acc[3][1] = __builtin_amdgcn_mfma_f32_16x16x32_bf16(af3, v1, acc[3][1], 0, 0, 0); \
    acc[3][2] = __builtin_amdgcn_mfma_f32_16x16x32_bf16(af3, v2, acc[3][2], 0, 0, 0); \
    acc[3][3] = __builtin_amdgcn_mfma_f32_16x16x32_bf16(af3, v3, acc[3][3], 0, 0, 0); \
    lac[3]    = __builtin_amdgcn_mfma_f32_16x16x32_bf16(af3, ones, lac[3], 0, 0, 0); \
} while (0)

__global__ __launch_bounds__(512, 2) void attn_fused(
    const ushort_t* __restrict__ Qbf, const ushort_t* __restrict__ Kfrag,
    const ushort_t* __restrict__ Vfrag,
    const void* __restrict__ x, const void* __restrict__ gamma,
    void* __restrict__ out, const int* __restrict__ flag)
{
    __shared__ float sO[64][65];
    __shared__ float sL[64];
    const int isf = flag[0];
    const int tid = threadIdx.x;
    const int lane = tid & 63;
    const int w = tid >> 6;
    const int cl = lane & 15, h = lane >> 4;
    const int q0 = blockIdx.x * 64;
    const int b = blockIdx.y;
    const size_t bN = (size_t)b * NN;

    for (int i = tid; i < 64 * 65; i += 512) (&sO[0][0])[i] = 0.f;
    if (tid < 64) sL[tid] = 0.f;
    __syncthreads();

    bf16x8 zero8;
#pragma unroll
    for (int j = 0; j < 8; ++j) zero8[j] = 0;
    bf16x8 qb[QT];
#pragma unroll
    for (int t = 0; t < QT; ++t) {
        bf16x8 z = zero8;
        if (h == 0) z = *(const bf16x8*)&Qbf[(bN + q0 + t * 16 + cl) * 8];
        qb[t] = z;
    }
    bf16x8 ones;
#pragma unroll
    for (int j = 0; j < 8; ++j) ones[j] = (short)0x3F80;

    const f32x4 zf = {0.f, 0.f, 0.f, 0.f};
    f32x4 acc[QT][4];
    f32x4 lac[QT];
#pragma unroll
    for (int t = 0; t < QT; ++t) {
        lac[t] = zf;
#pragma unroll
        for (int ct = 0; ct < 4; ++ct) acc[t][ct] = zf;
    }

    const ushort_t* Kb = Kfrag + bN * 32;
    const ushort_t* Vb = Vfrag + bN * 64;

    // per-lane element offsets (coalesced: lane*16B), set reload stride 16 blocks
    uint_t koA = (uint_t)w * 1024 + lane * 8;
    uint_t voA = (uint_t)w * 2048 + lane * 8;
    uint_t koB = koA + 8 * 1024;
    uint_t voB = voA + 8 * 2048;
    int baA = w, baB = w + 8;

    bf16x8 ka0A, ka1A, vA0, vA1, vA2, vA3;
    bf16x8 ka0B, ka1B, vB0, vB1, vB2, vB3;

    LOADK(ka0A, ka1A, koA); LOADV(vA0, vA1, vA2, vA3, voA);
    baA += 16; if (baA < NBLK32) { koA += KSTEP; voA += VSTEP; }

    const int cnt = (w < 2) ? 32 : 31;     // 250 = 8*31 + 2
    const int pairs = cnt >> 1;
    for (int p = 0; p < pairs; ++p) {
        LOADK(ka0B, ka1B, koB); LOADV(vB0, vB1, vB2, vB3, voB);
        baB += 16; if (baB < NBLK32) { koB += KSTEP; voB += VSTEP; }
        COMPUTE(ka0A, ka1A, vA0, vA1, vA2, vA3);
        LOADK(ka0A, ka1A, koA); LOADV(vA0, vA1, vA2, vA3, voA);
        baA += 16; if (baA < NBLK32) { koA += KSTEP; voA += VSTEP; }
        COMPUTE(ka0B, ka1B, vB0, vB1, vB2, vB3);
    }
    if (cnt & 1) COMPUTE(ka0A, ka1A, vA0, vA1, vA2, vA3);

    // combine 8 waves' partials in LDS
#pragma unroll
    for (int t = 0; t < QT; ++t) {
#pragma unroll
        for (int ct = 0; ct < 4; ++ct)
#pragma unroll
            for (int r = 0; r < 4; ++r)
                atomicAdd(&sO[t * 16 + 4 * h + r][ct * 16 + cl], acc[t][ct][r]);
        if (cl == 0) {
#pragma unroll
            for (int r = 0; r < 4; ++r)
                atomicAdd(&sL[t * 16 + 4 * h + r], lac[t][r]);
        }
    }
    __syncthreads();

    // epilogue: out = gamma*O/l + x, nontemporal (protect K/V in L2)
    const float g = loadF(gamma, 0, isf);
    const int qq = tid & 63;
    const int crow = tid >> 6;
    const float rL = 1.0f / sL[qq];
#pragma unroll
    for (int p = 0; p < 8; ++p) {
        const int c = p * 8 + crow;
        const size_t idx = ((size_t)b * CC + c) * NN + q0 + qq;
        if (isf) {
            const float xr = __builtin_nontemporal_load((const float*)x + idx);
            __builtin_nontemporal_store(g * sO[qq][c] * rL + xr, (float*)out + idx);
        } else {
            const float xr = __bfloat162float(((const __hip_bfloat16*)x)[idx]);
            ((__hip_bfloat16*)out)[idx] = __float2bfloat16(g * sO[qq][c] * rL + xr);
        }
    }
}

// ---------------------------------------------------------------------------
extern "C" void kernel_launch(void* const* d_in, const int* in_sizes, int n_in,
                              void* d_out, int out_size, void* d_ws, size_t ws_size,
                              hipStream_t stream)
{
    const void* x     = d_in[0];
    const void* Wq    = d_in[1];
    const void* bq    = d_in[2];
    const void* Wk    = d_in[3];
    const void* bk    = d_in[4];
    const void* Wv    = d_in[5];
    const void* bv    = d_in[6];
    const void* gamma = d_in[7];

    char* base = (char*)d_ws;
    int* flag = (int*)base;
    size_t off = 256;
    ushort_t* Qbf   = (ushort_t*)(base + off); off += (size_t)BB * NN * CQk * 2;
    ushort_t* Kfrag = (ushort_t*)(base + off); off += (size_t)BB * NN * 32 * 2;
    ushort_t* Vfrag = (ushort_t*)(base + off); off += (size_t)BB * NN * 64 * 2;

    detect_dtype<<<1, 64, 0, stream>>>(x, flag);

    qkv_kernel<<<dim3(250), 640, 0, stream>>>(x, Wq, bq, Wk, bk, Wv, bv,
                                              Qbf, Kfrag, Vfrag, flag);

    dim3 g2(NN / 64, BB);
    attn_fused<<<g2, 512, 0, stream>>>(Qbf, Kfrag, Vfrag, x, gamma, d_out, flag);
}

// Round 9
// 124.251 us; speedup vs baseline: 1.0299x; 1.0299x over previous
//
#include <hip/hip_runtime.h>
#include <hip/hip_bf16.h>

// FullAttention: B=2, C=64, Cq=8, N=20^3=8000. Inputs CONFIRMED f32 (r2).
#define BB 2
#define CC 64
#define CQk 8
#define NN 8000
#define QT 4          // 16-row q-tiles per wave (64 q per block)
#define NWAVE 8
#define NBLK32 250    // 8000/32 m-blocks

using f32x4  = __attribute__((ext_vector_type(4))) float;
using bf16x8 = __attribute__((ext_vector_type(8))) short;
typedef unsigned short ushort_t;
typedef unsigned int uint_t;

__device__ __forceinline__ ushort_t f2bf(float f) {
    __hip_bfloat16 h = __float2bfloat16(f);
    return *reinterpret_cast<ushort_t*>(&h);
}

// 2^x via compiler-visible trans-op intrinsic (hazard-safe; raw asm NaN'd r5).
__device__ __forceinline__ float exp2_fast(float x) {
#if __has_builtin(__builtin_amdgcn_exp2f)
    return __builtin_amdgcn_exp2f(x);
#else
    return exp2f(x);
#endif
}

// pack two f32 -> u32 of 2 bf16 (round-half-up). Valid for finite positives.
__device__ __forceinline__ uint_t pack_bf16(float a, float b) {
    const uint_t ua = __builtin_bit_cast(uint_t, a) + 0x8000u;
    const uint_t ub = __builtin_bit_cast(uint_t, b) + 0x8000u;
    return (ua >> 16) | (ub & 0xFFFF0000u);
}

// ---------------------------------------------------------------------------
__global__ void detect_dtype(const void* __restrict__ x, int* __restrict__ flag)
{
    const float* xf = (const float*)x;
    const int t = threadIdx.x;
    const float a = fabsf(xf[t * 8]);
    const int ok = (a > 9.765625e-4f && a < 16.0f) ? 1 : 0;
    const unsigned long long m = __ballot(ok);
    if (t == 0) flag[0] = (__popcll(m) >= 48) ? 1 : 0;
}

__device__ __forceinline__ float loadF(const void* p, size_t i, int isf) {
    return isf ? ((const float*)p)[i]
               : __bfloat162float(((const __hip_bfloat16*)p)[i]);
}

// ---------------------------------------------------------------------------
// Kernel 1: QKV projection -> fragment-major K/V, now with LDS-staged assembly
// so ALL global writes are coalesced 16B/lane. 250 blocks x 640 thr (10 waves).
// Compute phase: wave rg: rg0 -> Q rows (written direct, coalesced), rg1 -> K
// rows into sK LDS, rg2..9 -> V rows into sV LDS. Barrier. Gather phase:
// t<512: one Vfrag word each; t in [512,640): two Kfrag words each.
// Layouts (r8-verified by pass):
//   Kfrag[b][mblk][j][lane'][8]: lane'<16 holds K[mblk*32+j*16+lane'][0..7], else 0
//   Vfrag[b][mblk][ct][lane'=hv*16+cl'][8]: elem iv = V[ct*16+cl'][mblk*32+4hv+(iv&3)+16(iv>>2)]
// ---------------------------------------------------------------------------
__global__ __launch_bounds__(640) void qkv_kernel(
    const void* __restrict__ x,
    const void* __restrict__ Wq, const void* __restrict__ bq,
    const void* __restrict__ Wk, const void* __restrict__ bk,
    const void* __restrict__ Wv, const void* __restrict__ bv,
    ushort_t* __restrict__ Qbf, ushort_t* __restrict__ Kfrag,
    ushort_t* __restrict__ Vfrag, const int* __restrict__ flag)
{
    __shared__ float sW[80][CC];     // 20.5 KB
    __shared__ float sB[80];
    __shared__ float sX[CC][64];     // 16.4 KB
    __shared__ float sV[CC][65];     // 16.6 KB (+1 pad: gather reads <=4-way)
    __shared__ float sK[8][65];      //  2.1 KB
    const int isf = flag[0];
    const int t = threadIdx.x;

    for (int i = t; i < 80 * CC; i += 640) {
        const int r = i >> 6, c = i & 63;
        float w;
        if (r < CQk)          w = loadF(Wq, (size_t)r * CC + c, isf);
        else if (r < 2 * CQk) w = loadF(Wk, (size_t)(r - CQk) * CC + c, isf);
        else                  w = loadF(Wv, (size_t)(r - 2 * CQk) * CC + c, isf);
        sW[r][c] = w;
    }
    if (t < 80) {
        float bias;
        if (t < CQk)          bias = loadF(bq, t, isf);
        else if (t < 2 * CQk) bias = loadF(bk, t - CQk, isf);
        else                  bias = loadF(bv, t - 2 * CQk, isf);
        sB[t] = bias;
    }
    const int blk = blockIdx.x;            // 0..249 (125 per batch)
    const int b = blk / 125;
    const int n0loc = (blk % 125) * 64;    // batch-local position base
    for (int i = t; i < CC * 64; i += 640) {
        const int c = i >> 6, nl = i & 63;
        sX[c][nl] = loadF(x, (size_t)b * CC * NN + (size_t)c * NN + n0loc + nl, isf);
    }
    __syncthreads();

    // ---- compute phase ----
    {
        const int rg = t >> 6;             // wave 0..9 -> rows rg*8..+7
        const int nl = t & 63;
        const int r0 = rg * 8;

        float xv[CC];
#pragma unroll
        for (int c = 0; c < CC; ++c) xv[c] = sX[c][nl];

        float acc[8];
#pragma unroll
        for (int rr = 0; rr < 8; ++rr) {
            const f32x4* w4 = (const f32x4*)&sW[r0 + rr][0];
            float a0 = 0.f, a1 = 0.f, a2 = 0.f, a3 = 0.f;
#pragma unroll
            for (int c4 = 0; c4 < 16; ++c4) {
                const f32x4 wv = w4[c4];
                a0 += wv.x * xv[c4 * 4 + 0];
                a1 += wv.y * xv[c4 * 4 + 1];
                a2 += wv.z * xv[c4 * 4 + 2];
                a3 += wv.w * xv[c4 * 4 + 3];
            }
            acc[rr] = sB[r0 + rr] + ((a0 + a1) + (a2 + a3));
        }

        if (rg == 0) {                     // Q: direct coalesced 16B store
            bf16x8 pq;
#pragma unroll
            for (int j = 0; j < 8; ++j) pq[j] = (short)f2bf(acc[j] * 1.44269504089f);
            *(bf16x8*)&Qbf[((size_t)b * NN + n0loc + nl) * 8] = pq;
        } else if (rg == 1) {              // K rows -> LDS (banks: c+nl, 2/bank free)
#pragma unroll
            for (int rr = 0; rr < 8; ++rr) sK[rr][nl] = acc[rr];
        } else {                           // V rows -> LDS
            const int c0 = (rg - 2) * 8;
#pragma unroll
            for (int rr = 0; rr < 8; ++rr) sV[c0 + rr][nl] = acc[rr];
        }
    }
    __syncthreads();

    // ---- gather phase: coalesced fragment stores ----
    const int mblk0 = n0loc >> 5;          // 2 mblks per block
    if (t < 512) {                         // V: one bf16x8 fragment word each
        const int mblk = t >> 8, ct = (t >> 6) & 3, lanep = t & 63;
        const int hp = lanep >> 4, clp = lanep & 15;
        const int c = ct * 16 + clp;
        bf16x8 pv;
#pragma unroll
        for (int iv = 0; iv < 8; ++iv) {
            const int nl = mblk * 32 + 4 * hp + (iv & 3) + ((iv >> 2) << 4);
            pv[iv] = (short)f2bf(sV[c][nl]);
        }
        *(bf16x8*)&Vfrag[(size_t)b * NN * 64
                         + ((size_t)((mblk0 + mblk) * 4 + ct) * 64 + lanep) * 8] = pv;
    } else {                               // K: two fragment words each (128 thr x 2)
#pragma unroll
        for (int rep = 0; rep < 2; ++rep) {
            const int f = (t - 512) + rep * 128;   // 0..255
            const int mblk = f >> 7, j = (f >> 6) & 1, lanep = f & 63;
            bf16x8 pk;
            if (lanep < 16) {
                const int nl = mblk * 32 + j * 16 + lanep;
#pragma unroll
                for (int kk = 0; kk < 8; ++kk) pk[kk] = (short)f2bf(sK[kk][nl]);
            } else {
#pragma unroll
                for (int kk = 0; kk < 8; ++kk) pk[kk] = 0;
            }
            *(bf16x8*)&Kfrag[(size_t)b * NN * 32
                             + ((size_t)((mblk0 + mblk) * 2 + j) * 64 + lanep) * 8] = pk;
        }
    }
}

// ---------------------------------------------------------------------------
// Kernel 2: fused MFMA flash attention. grid (125,B), 8 waves, 2-deep ping-pong
// with sched_barrier(0) fences so the scheduler cannot sink prefetch loads
// into/past COMPUTE (r8 suspicion: live-range shrinking collapsed the pipeline).
// ---------------------------------------------------------------------------
#define KSTEP (16 * 1024)   // 16 mblks * 2 j * 64 lanes * 8 elems
#define VSTEP (16 * 2048)   // 16 mblks * 4 ct * 64 lanes * 8 elems

#define LOADK(d0, d1, ko) do { \
    d0 = *(const bf16x8*)(Kb + (ko)); \
    d1 = *(const bf16x8*)(Kb + (ko) + 512); } while (0)

#define LOADV(v0, v1, v2, v3, vo) do { \
    v0 = *(const bf16x8*)(Vb + (vo)); \
    v1 = *(const bf16x8*)(Vb + (vo) + 512); \
    v2 = *(const bf16x8*)(Vb + (vo) + 1024); \
    v3 = *(const bf16x8*)(Vb + (vo) + 1536); } while (0)

#define MKAF(af, eA, eB) do { \
    union { uint_t u[4]; bf16x8 v; } _u; \
    _u.u[0] = pack_bf16(exp2_fast(eA[0]), exp2_fast(eA[1])); \
    _u.u[1] = pack_bf16(exp2_fast(eA[2]), exp2_fast(eA[3])); \
    _u.u[2] = pack_bf16(exp2_fast(eB[0]), exp2_fast(eB[1])); \
    _u.u[3] = pack_bf16(exp2_fast(eB[2]), exp2_fast(eB[3])); \
    af = _u.v; } while (0)

#define COMPUTE(ka0, ka1, v0, v1, v2, v3) do { \
    f32x4 e00 = __builtin_amdgcn_mfma_f32_16x16x32_bf16(ka0, qb[0], zf, 0, 0, 0); \
    f32x4 e10 = __builtin_amdgcn_mfma_f32_16x16x32_bf16(ka1, qb[0], zf, 0, 0, 0); \
    f32x4 e01 = __builtin_amdgcn_mfma_f32_16x16x32_bf16(ka0, qb[1], zf, 0, 0, 0); \
    f32x4 e11 = __builtin_amdgcn_mfma_f32_16x16x32_bf16(ka1, qb[1], zf, 0, 0, 0); \
    f32x4 e02 = __builtin_amdgcn_mfma_f32_16x16x32_bf16(ka0, qb[2], zf, 0, 0, 0); \
    f32x4 e12 = __builtin_amdgcn_mfma_f32_16x16x32_bf16(ka1, qb[2], zf, 0, 0, 0); \
    f32x4 e03 = __builtin_amdgcn_mfma_f32_16x16x32_bf16(ka0, qb[3], zf, 0, 0, 0); \
    f32x4 e13 = __builtin_amdgcn_mfma_f32_16x16x32_bf16(ka1, qb[3], zf, 0, 0, 0); \
    bf16x8 af0, af1, af2, af3; \
    MKAF(af0, e00, e10); MKAF(af1, e01, e11); \
    MKAF(af2, e02, e12); MKAF(af3, e03, e13); \
    acc[0][0] = __builtin_amdgcn_mfma_f32_16x16x32_bf16(af0, v0, acc[0][0], 0, 0, 0); \
    acc[0][1] = __builtin_amdgcn_mfma_f32_16x16x32_bf16(af0, v1, acc[0][1], 0, 0, 0); \
    acc[0][2] = __builtin_amdgcn_mfma_f32_16x16x32_bf16(af0, v2, acc[0][2], 0, 0, 0); \
    acc[0][3] = __builtin_amdgcn_mfma_f32_16x16x32_bf16(af0, v3, acc[0][3], 0, 0, 0); \
    lac[0]    = __builtin_amdgcn_mfma_f32_16x16x32_bf16(af0, ones, lac[0], 0, 0, 0); \
    acc[1][0] = __builtin_amdgcn_mfma_f32_16x16x32_bf16(af1, v0, acc[1][0], 0, 0, 0); \
    acc[1][1] = __builtin_amdgcn_mfma_f32_16x16x32_bf16(af1, v1, acc[1][1], 0, 0, 0); \
    acc[1][2] = __builtin_amdgcn_mfma_f32_16x16x32_bf16(af1, v2, acc[1][2], 0, 0, 0); \
    acc[1][3] = __builtin_amdgcn_mfma_f32_16x16x32_bf16(af1, v3, acc[1][3], 0, 0, 0); \
    lac[1]    = __builtin_amdgcn_mfma_f32_16x16x32_bf16(af1, ones, lac[1], 0, 0, 0); \
    acc[2][0] = __builtin_amdgcn_mfma_f32_16x16x32_bf16(af2, v0, acc[2][0], 0, 0, 0); \
    acc[2][1] = __builtin_amdgcn_mfma_f32_16x16x32_bf16(af2, v1, acc[2][1], 0, 0, 0); \
    acc[2][2] = __builtin_amdgcn_mfma_f32_16x16x32_bf16(af2, v2, acc[2][2], 0, 0, 0); \
    acc[2][3] = __builtin_amdgcn_mfma_f32_16x16x32_bf16(af2, v3, acc[2][3], 0, 0, 0); \
    lac[2]    = __builtin_amdgcn_mfma_f32_16x16x32_bf16(af2, ones, lac[2], 0, 0, 0); \
    acc[3][0] = __builtin_amdgcn_mfma_f32_16x16x32_bf16(af3, v0, acc[3][0], 0, 0, 0); \
    acc[3][1] = __builtin_amdgcn_mfma_f32_16x16x32_bf16(af3, v1, acc[3][1], 0, 0, 0); \
    acc[3][2] = __builtin_amdgcn_mfma_f32_16x16x32_bf16(af3, v2, acc[3][2], 0, 0, 0); \
    acc[3][3] = __builtin_amdgcn_mfma_f32_16x16x32_bf16(af3, v3, acc[3][3], 0, 0, 0); \
    lac[3]    = __builtin_amdgcn_mfma_f32_16x16x32_bf16(af3, ones, lac[3], 0, 0, 0); \
} while (0)

#define SBAR() __builtin_amdgcn_sched_barrier(0)

__global__ __launch_bounds__(512, 2) void attn_fused(
    const ushort_t* __restrict__ Qbf, const ushort_t* __restrict__ Kfrag,
    const ushort_t* __restrict__ Vfrag,
    const void* __restrict__ x, const void* __restrict__ gamma,
    void* __restrict__ out, const int* __restrict__ flag)
{
    __shared__ float sO[64][65];
    __shared__ float sL[64];
    const int isf = flag[0];
    const int tid = threadIdx.x;
    const int lane = tid & 63;
    const int w = tid >> 6;
    const int cl = lane & 15, h = lane >> 4;
    const int q0 = blockIdx.x * 64;
    const int b = blockIdx.y;
    const size_t bN = (size_t)b * NN;

    for (int i = tid; i < 64 * 65; i += 512) (&sO[0][0])[i] = 0.f;
    if (tid < 64) sL[tid] = 0.f;
    __syncthreads();

    bf16x8 zero8;
#pragma unroll
    for (int j = 0; j < 8; ++j) zero8[j] = 0;
    bf16x8 qb[QT];
#pragma unroll
    for (int t = 0; t < QT; ++t) {
        bf16x8 z = zero8;
        if (h == 0) z = *(const bf16x8*)&Qbf[(bN + q0 + t * 16 + cl) * 8];
        qb[t] = z;
    }
    bf16x8 ones;
#pragma unroll
    for (int j = 0; j < 8; ++j) ones[j] = (short)0x3F80;

    const f32x4 zf = {0.f, 0.f, 0.f, 0.f};
    f32x4 acc[QT][4];
    f32x4 lac[QT];
#pragma unroll
    for (int t = 0; t < QT; ++t) {
        lac[t] = zf;
#pragma unroll
        for (int ct = 0; ct < 4; ++ct) acc[t][ct] = zf;
    }

    const ushort_t* Kb = Kfrag + bN * 32;
    const ushort_t* Vb = Vfrag + bN * 64;

    uint_t koA = (uint_t)w * 1024 + lane * 8;
    uint_t voA = (uint_t)w * 2048 + lane * 8;
    uint_t koB = koA + 8 * 1024;
    uint_t voB = voA + 8 * 2048;
    int baA = w, baB = w + 8;

    bf16x8 ka0A, ka1A, vA0, vA1, vA2, vA3;
    bf16x8 ka0B, ka1B, vB0, vB1, vB2, vB3;

    LOADK(ka0A, ka1A, koA); LOADV(vA0, vA1, vA2, vA3, voA);
    baA += 16; if (baA < NBLK32) { koA += KSTEP; voA += VSTEP; }
    SBAR();

    const int cnt = (w < 2) ? 32 : 31;     // 250 = 8*31 + 2
    const int pairs = cnt >> 1;
    for (int p = 0; p < pairs; ++p) {
        LOADK(ka0B, ka1B, koB); LOADV(vB0, vB1, vB2, vB3, voB);
        baB += 16; if (baB < NBLK32) { koB += KSTEP; voB += VSTEP; }
        SBAR();                            // loads pinned above
        COMPUTE(ka0A, ka1A, vA0, vA1, vA2, vA3);
        SBAR();
        LOADK(ka0A, ka1A, koA); LOADV(vA0, vA1, vA2, vA3, voA);
        baA += 16; if (baA < NBLK32) { koA += KSTEP; voA += VSTEP; }
        SBAR();
        COMPUTE(ka0B, ka1B, vB0, vB1, vB2, vB3);
        SBAR();
    }
    if (cnt & 1) COMPUTE(ka0A, ka1A, vA0, vA1, vA2, vA3);

    // combine 8 waves' partials in LDS
#pragma unroll
    for (int t = 0; t < QT; ++t) {
#pragma unroll
        for (int ct = 0; ct < 4; ++ct)
#pragma unroll
            for (int r = 0; r < 4; ++r)
                atomicAdd(&sO[t * 16 + 4 * h + r][ct * 16 + cl], acc[t][ct][r]);
        if (cl == 0) {
#pragma unroll
            for (int r = 0; r < 4; ++r)
                atomicAdd(&sL[t * 16 + 4 * h + r], lac[t][r]);
        }
    }
    __syncthreads();

    // epilogue: out = gamma*O/l + x, nontemporal (protect K/V in L2)
    const float g = loadF(gamma, 0, isf);
    const int qq = tid & 63;
    const int crow = tid >> 6;
    const float rL = 1.0f / sL[qq];
#pragma unroll
    for (int p = 0; p < 8; ++p) {
        const int c = p * 8 + crow;
        const size_t idx = ((size_t)b * CC + c) * NN + q0 + qq;
        if (isf) {
            const float xr = __builtin_nontemporal_load((const float*)x + idx);
            __builtin_nontemporal_store(g * sO[qq][c] * rL + xr, (float*)out + idx);
        } else {
            const float xr = __bfloat162float(((const __hip_bfloat16*)x)[idx]);
            ((__hip_bfloat16*)out)[idx] = __float2bfloat16(g * sO[qq][c] * rL + xr);
        }
    }
}

// ---------------------------------------------------------------------------
extern "C" void kernel_launch(void* const* d_in, const int* in_sizes, int n_in,
                              void* d_out, int out_size, void* d_ws, size_t ws_size,
                              hipStream_t stream)
{
    const void* x     = d_in[0];
    const void* Wq    = d_in[1];
    const void* bq    = d_in[2];
    const void* Wk    = d_in[3];
    const void* bk    = d_in[4];
    const void* Wv    = d_in[5];
    const void* bv    = d_in[6];
    const void* gamma = d_in[7];

    char* base = (char*)d_ws;
    int* flag = (int*)base;
    size_t off = 256;
    ushort_t* Qbf   = (ushort_t*)(base + off); off += (size_t)BB * NN * CQk * 2;
    ushort_t* Kfrag = (ushort_t*)(base + off); off += (size_t)BB * NN * 32 * 2;
    ushort_t* Vfrag = (ushort_t*)(base + off); off += (size_t)BB * NN * 64 * 2;

    detect_dtype<<<1, 64, 0, stream>>>(x, flag);

    qkv_kernel<<<dim3(250), 640, 0, stream>>>(x, Wq, bq, Wk, bk, Wv, bv,
                                              Qbf, Kfrag, Vfrag, flag);

    dim3 g2(NN / 64, BB);
    attn_fused<<<g2, 512, 0, stream>>>(Qbf, Kfrag, Vfrag, x, gamma, d_out, flag);
}